// Round 13
// baseline (76.289 us; speedup 1.0000x reference)
//
#include <hip/hip_runtime.h>
#include <math.h>

#define BATCH 2
#define NPTS  1024
#define NC    32
#define DIN   8
#define DOUT  8
#define ATILE 64                          // a's per block (4 waves x 16)
#define NCHUNK 64                         // b-splits
#define BPW   (NPTS / NCHUNK)             // 16 b's per block
#define OUT_ELEMS (BATCH * NPTS * DOUT)   // 16384
#define NE4   (OUT_ELEMS / 4)             // 4096
#define LOG2E 1.4426950408889634f
#define G_BYTES ((size_t)BATCH * NPTS * 64 * 16)   // 2 MB of half8 B-frags

typedef _Float16 half8 __attribute__((ext_vector_type(8)));
typedef __fp16   fp16x2 __attribute__((ext_vector_type(2)));
typedef float    floatx4 __attribute__((ext_vector_type(4)));

#if __has_builtin(__builtin_amdgcn_exp2f)
#define EXP2F(x) __builtin_amdgcn_exp2f(x)
#else
#define EXP2F(x) exp2f(x)
#endif

// ---------------------------------------------------------------------------
// g_kernel (unchanged, R11/R12-verified): one-time build of B-frags in ws.
// ---------------------------------------------------------------------------
__global__ __launch_bounds__(256) void g_kernel(
        const float* __restrict__ feat,
        const float* __restrict__ W,
        half8*       __restrict__ gws) {
    const int e    = blockIdx.x * 256 + threadIdx.x;  // < BATCH*NPTS*64
    const int slot = e & 63;
    const int zb   = e >> 6;
    half8 gv = {};
    if (!(slot & 8)) {
        const int i   = slot & 7;
        const int oct = slot >> 4;
        const float* f = feat + (size_t)zb * DIN;
        const float4 f0 = *(const float4*)f;
        const float4 f1 = *(const float4*)(f + 4);
#pragma unroll
        for (int j = 0; j < 8; ++j) {
            const float* wr = W + ((oct * 8 + j) * DOUT + i) * DIN;
            const float4 wa = *(const float4*)wr;
            const float4 wb = *(const float4*)(wr + 4);
            float s = fmaf(wa.x, f0.x,
                      fmaf(wa.y, f0.y,
                      fmaf(wa.z, f0.z,
                      fmaf(wa.w, f0.w,
                      fmaf(wb.x, f1.x,
                      fmaf(wb.y, f1.y,
                      fmaf(wb.z, f1.z,
                             wb.w * f1.w)))))));
            gv[j] = (_Float16)s;
        }
    }
    gws[e] = gv;
}

// ---------------------------------------------------------------------------
// conv_mfma v5 — REGISTER-PREFETCH the B-frags (R12 post-mortem: ~540
// cyc/wave-b measured vs ~100 issue model -> per-iteration gws load was
// paying a full L2/LLC round trip serially; launch_bounds(256,4)'s 128-VGPR
// cap blocked hoisting). All 16 loads issued back-to-back into a register
// array (64 VGPR, one latency exposure per block), then pure-compute loop.
// launch_bounds (256,2) gives the allocator ~256 VGPR headroom.
// Exp math: R12's NaN-proof dual-seed recurrence (verified). Layouts
// byte-identical to R8..R12 (verified).
// ---------------------------------------------------------------------------
__global__ __launch_bounds__(256, 2) void conv_mfma(
        const float* __restrict__ geo,
        const half8* __restrict__ gws,
        float*       __restrict__ partial) {  // [NCHUNK][BATCH*NPTS][DOUT]
    const int t     = threadIdx.x;
    const int bid   = blockIdx.x;
    const int chunk = bid & (NCHUNK - 1);
    const int atile = (bid >> 6) & 15;
    const int z     = bid >> 10;

    const int b0 = chunk * BPW;
    const float* geoz = geo + (size_t)z * NPTS * 3;
    const float* bge  = geoz + b0 * 3;         // wave-uniform base

    const int lane = t & 63;
    const int wv   = t >> 6;
    const int m    = lane & 15;
    const int quad = lane >> 4;
    const int a0   = atile * ATILE + wv * 16;
    const int a    = a0 + m;

    const float ax = geoz[a * 3 + 0];
    const float ay = geoz[a * 3 + 1];
    const float az = geoz[a * 3 + 2];
    const float c0   = (float)(quad * 8);
    const float invw = (float)(NC - 1) / 3.5f;
    const float K2   = 0.13533528324f;         // exp(-2)
    const float K8   = 3.35462627903e-4f;      // exp(-8)

    const half8* gp = gws + ((size_t)(z * NPTS + b0)) * 64 + lane;

    // ---- prefetch ALL B-frags: 16 independent global_load_dwordx4 in
    // flight together -> one memory-latency exposure per block ----
    half8 bf[BPW];
#pragma unroll
    for (int b = 0; b < BPW; ++b)
        bf[b] = gp[(size_t)b * 64];

    floatx4 acc0 = {0.f, 0.f, 0.f, 0.f};
    floatx4 acc1 = {0.f, 0.f, 0.f, 0.f};

#pragma unroll
    for (int b = 0; b < BPW; ++b) {
        // wave-uniform geo (compile-time offsets under full unroll -> s_load)
        const float bx = bge[b * 3 + 0];
        const float by = bge[b * 3 + 1];
        const float bz = bge[b * 3 + 2];
        const float dx = bx - ax, dy = by - ay, dz = bz - az;
        const float u  = sqrtf(fmaf(dx, dx, fmaf(dy, dy, fmaf(dz, dz, 1e-12f)))) * invw;
        const float tc = fminf(u - c0, 11.0f);
        // dual-seed recurrence (R12-verified, NaN-proof):
        const float e0 = EXP2F((tc * tc) * (-LOG2E));
        const float t4 = tc - 4.0f;
        const float e4 = EXP2F((t4 * t4) * (-LOG2E));
        const float r0 = EXP2F(fmaf(2.0f * LOG2E, tc, -LOG2E));   // exp(2tc-1)
        const float r4 = r0 * K8;                                  // exp(2t4-1)
        const float e1 = e0 * r0;  const float r1 = r0 * K2;
        const float e2 = e1 * r1;  const float r2 = r1 * K2;
        const float e3 = e2 * r2;
        const float e5 = e4 * r4;  const float r5 = r4 * K2;
        const float e6 = e5 * r5;  const float r6 = r5 * K2;
        const float e7 = e6 * r6;
        union { half8 v; fp16x2 h[4]; } af;
        af.h[0] = __builtin_amdgcn_cvt_pkrtz(e0, e1);
        af.h[1] = __builtin_amdgcn_cvt_pkrtz(e2, e3);
        af.h[2] = __builtin_amdgcn_cvt_pkrtz(e4, e5);
        af.h[3] = __builtin_amdgcn_cvt_pkrtz(e6, e7);
        if (b & 1)
            acc1 = __builtin_amdgcn_mfma_f32_16x16x32_f16(af.v, bf[b], acc1, 0, 0, 0);
        else
            acc0 = __builtin_amdgcn_mfma_f32_16x16x32_f16(af.v, bf[b], acc0, 0, 0, 0);
    }

    // ---- epilogue: D col = i (lane&15, keep <8), row = quad*4 + reg ----
    if (m < 8) {
        float* pp = partial + (size_t)chunk * OUT_ELEMS
                  + ((size_t)(z * NPTS + a0 + quad * 4)) * DOUT + m;
#pragma unroll
        for (int r = 0; r < 4; ++r)
            pp[r * DOUT] = acc0[r] + acc1[r];
    }
}

// ---------------------------------------------------------------------------
// reduce_partials (unchanged): 256 blocks, 16 f4-elems x 16 chunk-groups.
// ---------------------------------------------------------------------------
template <int NCH>
__global__ __launch_bounds__(256) void reduce_partials(
        const float* __restrict__ partial,
        const int*   __restrict__ n_norm,
        float*       __restrict__ out) {
    const int tx = threadIdx.x & 15;
    const int ty = threadIdx.x >> 4;
    const int e4 = blockIdx.x * 16 + tx;
    const float4* p = (const float4*)partial;

    float4 s = make_float4(0.f, 0.f, 0.f, 0.f);
#pragma unroll
    for (int j = 0; j < NCH / 16; ++j) {
        float4 v = p[(size_t)(j * 16 + ty) * NE4 + e4];
        s.x += v.x; s.y += v.y; s.z += v.z; s.w += v.w;
    }

    __shared__ float4 red[16][16];
    red[ty][tx] = s;
    __syncthreads();

    if (ty == 0) {
        float4 tot = red[0][tx];
#pragma unroll
        for (int j = 1; j < 16; ++j) {
            float4 v = red[j][tx];
            tot.x += v.x; tot.y += v.y; tot.z += v.z; tot.w += v.w;
        }
        const float scale = 1.0f / sqrtf((float)n_norm[0]);
        ((float4*)out)[e4] = make_float4(tot.x * scale, tot.y * scale,
                                         tot.z * scale, tot.w * scale);
    }
}

// ---------------------------------------------------------------------------
extern "C" void kernel_launch(void* const* d_in, const int* in_sizes, int n_in,
                              void* d_out, int out_size, void* d_ws, size_t ws_size,
                              hipStream_t stream) {
    const float* feat   = (const float*)d_in[0];   // [2,1024,8]
    const float* geo    = (const float*)d_in[1];   // [2,1024,3]
    const float* W      = (const float*)d_in[2];   // [32,8,8]
    const int*   n_norm = (const int*)  d_in[3];   // scalar 1024
    float* out = (float*)d_out;                    // [2,1024,8]

    half8* gws     = (half8*)d_ws;                              // 2 MB
    float* partial = (float*)((char*)d_ws + G_BYTES);           // 4 MB

    g_kernel<<<(BATCH * NPTS * 64) / 256, 256, 0, stream>>>(feat, W, gws);
    conv_mfma<<<BATCH * 16 * NCHUNK, 256, 0, stream>>>(geo, gws, partial);
    reduce_partials<NCHUNK><<<NE4 / 16, 256, 0, stream>>>(partial, n_norm, out);
}